// Round 1
// baseline (743.774 us; speedup 1.0000x reference)
//
#include <hip/hip_runtime.h>
#include <hip/hip_bf16.h>
#include <stdint.h>
#include <stddef.h>

#define T_TOK 2048
#define H_DIM 1024
#define I_DIM 4096
#define E_NUM 8
#define R_TOT 4096  // TOP_K * T_TOK

typedef __attribute__((ext_vector_type(4))) float f32x4;
typedef __attribute__((ext_vector_type(8))) __bf16 bf16x8;

__device__ __forceinline__ unsigned short f2b(float f) {
  __hip_bfloat16 h = __float2bfloat16(f);
  return __builtin_bit_cast(unsigned short, h);
}

__device__ __forceinline__ void gll16(const void* g, void* l) {
  __builtin_amdgcn_global_load_lds(
      (const __attribute__((address_space(1))) unsigned int*)g,
      (__attribute__((address_space(3))) unsigned int*)l, 16, 0, 0);
}

// ---------------- router (fp32, exact-ish selection) ----------------
__global__ __launch_bounds__(64) void k_router(
    const float* __restrict__ x, const float* __restrict__ gate,
    int* __restrict__ top_e, float* __restrict__ top_w, int* __restrict__ cnt)
{
  int t = blockIdx.x, lane = threadIdx.x;
  const float* xr = x + (size_t)t * H_DIM;
  float acc[E_NUM];
#pragma unroll
  for (int e = 0; e < E_NUM; e++) acc[e] = 0.f;
  for (int it = 0; it < H_DIM / 64; it++) {
    int h = it * 64 + lane;
    float xv = xr[h];
    const float4* gp = (const float4*)(gate + (size_t)h * E_NUM);
    float4 g0 = gp[0], g1 = gp[1];
    acc[0] += xv * g0.x; acc[1] += xv * g0.y; acc[2] += xv * g0.z; acc[3] += xv * g0.w;
    acc[4] += xv * g1.x; acc[5] += xv * g1.y; acc[6] += xv * g1.z; acc[7] += xv * g1.w;
  }
#pragma unroll
  for (int e = 0; e < E_NUM; e++) {
    for (int off = 32; off > 0; off >>= 1) acc[e] += __shfl_xor(acc[e], off, 64);
  }
  if (lane == 0) {
    int e0 = 0; float l0 = acc[0];
#pragma unroll
    for (int e = 1; e < E_NUM; e++) if (acc[e] > l0) { l0 = acc[e]; e0 = e; }
    int e1 = -1; float l1 = -3.0e38f;
#pragma unroll
    for (int e = 0; e < E_NUM; e++) if (e != e0 && acc[e] > l1) { l1 = acc[e]; e1 = e; }
    float w0 = 1.f / (1.f + expf(l1 - l0));  // softmax over top-2 (l0 >= l1)
    top_e[2 * t] = e0; top_e[2 * t + 1] = e1;
    top_w[2 * t] = w0; top_w[2 * t + 1] = 1.f - w0;
    atomicAdd(&cnt[e0], 1); atomicAdd(&cnt[e1], 1);
  }
}

__global__ __launch_bounds__(64) void k_scan(const int* __restrict__ cnt, int* __restrict__ offs) {
  if (threadIdx.x == 0) {
    int o = 0;
#pragma unroll
    for (int e = 0; e < E_NUM; e++) { offs[e] = o; o += cnt[e]; }
    offs[E_NUM] = o;
  }
}

__global__ __launch_bounds__(256) void k_assign(
    const int* __restrict__ top_e, const float* __restrict__ top_w,
    const int* __restrict__ offs, int* __restrict__ cur,
    int* __restrict__ row_token, float* __restrict__ row_w)
{
  int t = blockIdx.x * 256 + threadIdx.x;
  if (t >= T_TOK) return;
#pragma unroll
  for (int k = 0; k < 2; k++) {
    int e = top_e[2 * t + k];
    int pos = atomicAdd(&cur[e], 1);
    int slot = offs[e] + pos;
    row_token[slot] = t;
    row_w[slot] = top_w[2 * t + k];
  }
}

// ---------------- x fp32 -> bf16 ----------------
__global__ __launch_bounds__(256) void k_cvt_x(const float* __restrict__ x,
                                               unsigned short* __restrict__ xb) {
  int i = blockIdx.x * 256 + threadIdx.x;  // exactly T*H/4 threads
  float4 v = ((const float4*)x)[i];
  ushort4 o;
  o.x = f2b(v.x); o.y = f2b(v.y); o.z = f2b(v.z); o.w = f2b(v.w);
  ((ushort4*)xb)[i] = o;
}

// ---------------- transpose + convert: src f32 [R][C] -> dst bf16 [C][R] ----------------
__global__ __launch_bounds__(256) void k_wt(const float* __restrict__ src,
                                            unsigned short* __restrict__ dst, int R, int C) {
  __shared__ unsigned short lds[64][66];
  size_t bo = (size_t)blockIdx.z * R * C;
  const float* s = src + bo;
  unsigned short* d = dst + bo;
  int row0 = blockIdx.y * 64, col0 = blockIdx.x * 64;
  int t = threadIdx.x;
#pragma unroll
  for (int rep = 0; rep < 4; rep++) {
    int g = rep * 256 + t;
    int r = g >> 4, c4 = g & 15;
    float4 v = *(const float4*)(s + (size_t)(row0 + r) * C + col0 + c4 * 4);
    lds[r][c4 * 4 + 0] = f2b(v.x);
    lds[r][c4 * 4 + 1] = f2b(v.y);
    lds[r][c4 * 4 + 2] = f2b(v.z);
    lds[r][c4 * 4 + 3] = f2b(v.w);
  }
  __syncthreads();
#pragma unroll
  for (int rep = 0; rep < 4; rep++) {
    int g = rep * 256 + t;
    int orow = g >> 4, oc4 = g & 15;
    ushort4 o;
    o.x = lds[oc4 * 4 + 0][orow];
    o.y = lds[oc4 * 4 + 1][orow];
    o.z = lds[oc4 * 4 + 2][orow];
    o.w = lds[oc4 * 4 + 3][orow];
    *(ushort4*)(d + (size_t)(col0 + orow) * R + row0 + oc4 * 4) = o;
  }
}

// ---------------- GEMM-A: [ne,1024] x (W1,W3)[1024,4096] -> silu(g)*u -> hid bf16 ----------------
// B^T inputs (w1t/w3t are [I][H]); 128x128 tile, BK=64, 4 waves, XOR-swizzled LDS via
// pre-swizzled global source (global_load_lds has linear wave-uniform dest).
__global__ __launch_bounds__(256) void k_gemm_a(
    const unsigned short* __restrict__ xb,
    const unsigned short* __restrict__ w1t,
    const unsigned short* __restrict__ w3t,
    const int* __restrict__ row_token,
    const int* __restrict__ offs,
    const int* __restrict__ cnt,
    unsigned short* __restrict__ hid)
{
  int e = blockIdx.z;
  int ne = cnt[e];
  int mt = blockIdx.y;
  if (mt * 128 >= ne) return;
  int n0 = blockIdx.x * 128;
  int off = offs[e];

  __shared__ unsigned short As[128 * 64];
  __shared__ unsigned short B1s[128 * 64];
  __shared__ unsigned short B2s[128 * 64];

  int tid = threadIdx.x;
  int wave = tid >> 6, lane = tid & 63;
  int wr = wave >> 1, wc = wave & 1;
  int srow = lane >> 3;
  int scg = (lane & 7) ^ srow;  // pre-swizzled source granule

  const unsigned short* w1e = w1t + (size_t)e * I_DIM * H_DIM;
  const unsigned short* w3e = w3t + (size_t)e * I_DIM * H_DIM;

  const unsigned short* ab[4];
  const unsigned short* b1b[4];
  const unsigned short* b2b[4];
#pragma unroll
  for (int c = 0; c < 4; c++) {
    int r = wave * 32 + c * 8 + srow;            // LDS row 0..127
    int rl = mt * 128 + r;
    int tok = (rl < ne) ? row_token[off + rl] : row_token[off];
    ab[c] = xb + (size_t)tok * H_DIM + scg * 8;
    b1b[c] = w1e + (size_t)(n0 + r) * H_DIM + scg * 8;
    b2b[c] = w3e + (size_t)(n0 + r) * H_DIM + scg * 8;
  }

  f32x4 accg[4][4], accu[4][4];
#pragma unroll
  for (int m = 0; m < 4; m++)
#pragma unroll
    for (int n = 0; n < 4; n++) { accg[m][n] = (f32x4)0.f; accu[m][n] = (f32x4)0.f; }

  unsigned short* asw = As + wave * 2048;
  unsigned short* b1w = B1s + wave * 2048;
  unsigned short* b2w = B2s + wave * 2048;

  for (int k0 = 0; k0 < H_DIM; k0 += 64) {
    __syncthreads();
#pragma unroll
    for (int c = 0; c < 4; c++) {
      gll16(ab[c] + k0, asw + c * 512);
      gll16(b1b[c] + k0, b1w + c * 512);
      gll16(b2b[c] + k0, b2w + c * 512);
    }
    __syncthreads();
#pragma unroll
    for (int ks = 0; ks < 2; ks++) {
      int gsw = ((ks * 4 + (lane >> 4)) ^ (lane & 7)) * 8;
      bf16x8 af[4], b1f[4], b2f[4];
#pragma unroll
      for (int m = 0; m < 4; m++)
        af[m] = *(const bf16x8*)(As + (wr * 64 + m * 16 + (lane & 15)) * 64 + gsw);
#pragma unroll
      for (int n = 0; n < 4; n++) {
        int r = (wc * 64 + n * 16 + (lane & 15)) * 64 + gsw;
        b1f[n] = *(const bf16x8*)(B1s + r);
        b2f[n] = *(const bf16x8*)(B2s + r);
      }
#pragma unroll
      for (int m = 0; m < 4; m++)
#pragma unroll
        for (int n = 0; n < 4; n++) {
          accg[m][n] = __builtin_amdgcn_mfma_f32_16x16x32_bf16(af[m], b1f[n], accg[m][n], 0, 0, 0);
          accu[m][n] = __builtin_amdgcn_mfma_f32_16x16x32_bf16(af[m], b2f[n], accu[m][n], 0, 0, 0);
        }
    }
  }

  int tcol = lane >> 4;
#pragma unroll
  for (int m = 0; m < 4; m++) {
#pragma unroll
    for (int j = 0; j < 4; j++) {
      int rl = mt * 128 + wr * 64 + m * 16 + tcol * 4 + j;
      if (rl < ne) {
        size_t rp = (size_t)(off + rl) * I_DIM + n0 + wc * 64 + (lane & 15);
#pragma unroll
        for (int n = 0; n < 4; n++) {
          float g = accg[m][n][j], u = accu[m][n][j];
          float s = g / (1.f + expf(-g));  // silu
          hid[rp + n * 16] = f2b(s * u);
        }
      }
    }
  }
}

// ---------------- GEMM-B: hid [ne,4096] x W2[4096,1024] -> weighted scatter-add ----------------
__global__ __launch_bounds__(256) void k_gemm_b(
    const unsigned short* __restrict__ hid,
    const unsigned short* __restrict__ w2t,
    const int* __restrict__ row_token,
    const float* __restrict__ row_w,
    const int* __restrict__ offs,
    const int* __restrict__ cnt,
    float* __restrict__ out)
{
  int e = blockIdx.z;
  int ne = cnt[e];
  int mt = blockIdx.y;
  if (mt * 128 >= ne) return;
  int n0 = blockIdx.x * 128;
  int off = offs[e];

  __shared__ unsigned short As[128 * 64];
  __shared__ unsigned short Bs[128 * 64];

  int tid = threadIdx.x;
  int wave = tid >> 6, lane = tid & 63;
  int wr = wave >> 1, wc = wave & 1;
  int srow = lane >> 3;
  int scg = (lane & 7) ^ srow;

  const unsigned short* w2e = w2t + (size_t)e * H_DIM * I_DIM;

  const unsigned short* ab[4];
  const unsigned short* bb[4];
#pragma unroll
  for (int c = 0; c < 4; c++) {
    int r = wave * 32 + c * 8 + srow;
    ab[c] = hid + (size_t)(off + mt * 128 + r) * I_DIM + scg * 8;  // hid padded +128 rows
    bb[c] = w2e + (size_t)(n0 + r) * I_DIM + scg * 8;
  }

  f32x4 acc[4][4];
#pragma unroll
  for (int m = 0; m < 4; m++)
#pragma unroll
    for (int n = 0; n < 4; n++) acc[m][n] = (f32x4)0.f;

  unsigned short* asw = As + wave * 2048;
  unsigned short* bsw = Bs + wave * 2048;

  for (int k0 = 0; k0 < I_DIM; k0 += 64) {
    __syncthreads();
#pragma unroll
    for (int c = 0; c < 4; c++) {
      gll16(ab[c] + k0, asw + c * 512);
      gll16(bb[c] + k0, bsw + c * 512);
    }
    __syncthreads();
#pragma unroll
    for (int ks = 0; ks < 2; ks++) {
      int gsw = ((ks * 4 + (lane >> 4)) ^ (lane & 7)) * 8;
      bf16x8 af[4], bf[4];
#pragma unroll
      for (int m = 0; m < 4; m++)
        af[m] = *(const bf16x8*)(As + (wr * 64 + m * 16 + (lane & 15)) * 64 + gsw);
#pragma unroll
      for (int n = 0; n < 4; n++)
        bf[n] = *(const bf16x8*)(Bs + (wc * 64 + n * 16 + (lane & 15)) * 64 + gsw);
#pragma unroll
      for (int m = 0; m < 4; m++)
#pragma unroll
        for (int n = 0; n < 4; n++)
          acc[m][n] = __builtin_amdgcn_mfma_f32_16x16x32_bf16(af[m], bf[n], acc[m][n], 0, 0, 0);
    }
  }

  int tcol = lane >> 4;
#pragma unroll
  for (int m = 0; m < 4; m++) {
#pragma unroll
    for (int j = 0; j < 4; j++) {
      int rl = mt * 128 + wr * 64 + m * 16 + tcol * 4 + j;
      if (rl < ne) {
        int rg = off + rl;
        int tok = row_token[rg];
        float w = row_w[rg];
        float* op = out + (size_t)tok * H_DIM + n0 + wc * 64 + (lane & 15);
#pragma unroll
        for (int n = 0; n < 4; n++)
          atomicAdd(op + n * 16, acc[m][n][j] * w);
      }
    }
  }
}

extern "C" void kernel_launch(void* const* d_in, const int* in_sizes, int n_in,
                              void* d_out, int out_size, void* d_ws, size_t ws_size,
                              hipStream_t stream) {
  (void)in_sizes; (void)n_in; (void)out_size; (void)ws_size;
  const float* x = (const float*)d_in[0];
  const float* gate = (const float*)d_in[1];
  const float* w1 = (const float*)d_in[2];
  const float* w2 = (const float*)d_in[3];
  const float* w3 = (const float*)d_in[4];
  float* out = (float*)d_out;
  char* ws = (char*)d_ws;

  // ws layout (needs ~230 MB)
  int* cnt = (int*)(ws + 0);
  int* cur = (int*)(ws + 64);
  int* offs = (int*)(ws + 128);
  int* tope = (int*)(ws + 1024);
  float* topw = (float*)(ws + 1024 + 4 * 2 * T_TOK);
  int* rtok = (int*)(ws + 1024 + 8 * 2 * T_TOK);
  float* rw = (float*)(ws + 1024 + 8 * 2 * T_TOK + 4 * R_TOT);
  unsigned short* xb = (unsigned short*)(ws + (1 << 17));
  unsigned short* w1t = xb + (size_t)T_TOK * H_DIM;
  unsigned short* w3t = w1t + (size_t)E_NUM * I_DIM * H_DIM;
  unsigned short* w2t = w3t + (size_t)E_NUM * I_DIM * H_DIM;
  unsigned short* hid = w2t + (size_t)E_NUM * H_DIM * I_DIM;  // (R_TOT+128) x I_DIM

  hipMemsetAsync(ws, 0, 1024, stream);                                   // cnt/cur/offs
  hipMemsetAsync(out, 0, (size_t)T_TOK * H_DIM * sizeof(float), stream); // atomic target

  k_cvt_x<<<T_TOK * H_DIM / 4 / 256, 256, 0, stream>>>(x, xb);
  k_wt<<<dim3(I_DIM / 64, H_DIM / 64, E_NUM), 256, 0, stream>>>(w1, w1t, H_DIM, I_DIM);
  k_wt<<<dim3(I_DIM / 64, H_DIM / 64, E_NUM), 256, 0, stream>>>(w3, w3t, H_DIM, I_DIM);
  k_wt<<<dim3(H_DIM / 64, I_DIM / 64, E_NUM), 256, 0, stream>>>(w2, w2t, I_DIM, H_DIM);
  k_router<<<T_TOK, 64, 0, stream>>>(x, gate, tope, topw, cnt);
  k_scan<<<1, 64, 0, stream>>>(cnt, offs);
  k_assign<<<T_TOK / 256, 256, 0, stream>>>(tope, topw, offs, cur, rtok, rw);
  k_gemm_a<<<dim3(I_DIM / 128, 16, E_NUM), 256, 0, stream>>>(xb, w1t, w3t, rtok, offs, cnt, hid);
  k_gemm_b<<<dim3(H_DIM / 128, 16, E_NUM), 256, 0, stream>>>(hid, w2t, rtok, rw, offs, cnt, out);
}